// Round 1
// baseline (19.853 us; speedup 1.0000x reference)
//
#include <hip/hip_runtime.h>

// Problem constants (B=2, M=10, N=1024, D=128, H=8, HD=16).
// Key identity: softmax over axis m followed by sum over axis m == 1
// everywhere, so attn is all-ones and the output is rank-1 per batch:
//   out[b, n, :] = ((sum_n node_emb[b,n,:]) @ Wv + N*bv) @ out_w + out_b
// where Wv = Wqkv_w[:, 2D:3D], bv = Wqkv_b[2D:3D].
// prefer_emb / wq_p / wk_p do not affect the output at all.

#define BB 2
#define NN 1024
#define DD 128
#define TRIPLE (3 * DD)

// ---------------------------------------------------------------------------
// Kernel 1: ne_sum[b][d] = sum_n node_emb[b][n][d]
// 64 blocks x 128 threads; each block sums 32 rows, atomicAdd into ws.
// Lane d reads column d of consecutive rows -> each wave reads 256B
// contiguous per row (coalesced).
// ---------------------------------------------------------------------------
__global__ void k_colsum(const float* __restrict__ node,
                         float* __restrict__ ne_sum) {
    const int CH = 32;                 // rows per block
    int b = blockIdx.x >> 5;           // 32 chunks per batch
    int chunk = blockIdx.x & 31;
    int d = threadIdx.x;               // 0..127
    const float* p = node + ((size_t)b * NN + (size_t)chunk * CH) * DD + d;
    float acc = 0.f;
#pragma unroll
    for (int r = 0; r < CH; ++r) acc += p[r * DD];
    atomicAdd(&ne_sum[b * DD + d], acc);
}

// ---------------------------------------------------------------------------
// Kernel 2: tiny double GEMV.
//   v_sum[b][d] = sum_c ne_sum[b][c] * Wqkv_w[c][2D+d] + N * Wqkv_b[2D+d]
//   row[b][j]   = sum_c v_sum[b][c] * out_w[c][j] + out_b[j]
// One block, 256 threads (thread t -> b = t>>7, d = t&127).
// ---------------------------------------------------------------------------
__global__ void k_small(const float* __restrict__ ne_sum,
                        const float* __restrict__ Wqkv_w,
                        const float* __restrict__ Wqkv_b,
                        const float* __restrict__ out_w,
                        const float* __restrict__ out_b,
                        float* __restrict__ row) {
    __shared__ float s_ne[BB * DD];
    __shared__ float s_vs[BB * DD];
    int t = threadIdx.x;               // 0..255
    s_ne[t] = ne_sum[t];
    __syncthreads();

    int b = t >> 7;
    int d = t & (DD - 1);

    float acc = Wqkv_b[2 * DD + d] * (float)NN;
#pragma unroll 8
    for (int c = 0; c < DD; ++c)
        acc += s_ne[b * DD + c] * Wqkv_w[c * TRIPLE + 2 * DD + d];
    s_vs[t] = acc;
    __syncthreads();

    float r = out_b[d];
#pragma unroll 8
    for (int c = 0; c < DD; ++c)
        r += s_vs[b * DD + c] * out_w[c * DD + d];
    row[t] = r;
}

// ---------------------------------------------------------------------------
// Kernel 3: broadcast row[b][:] into all N rows of the output.
// 65536 float4 stores (2*1024*128 floats). Row data (1KB) stays in L2.
// ---------------------------------------------------------------------------
__global__ void k_bcast(const float* __restrict__ row,
                        float4* __restrict__ out4) {
    int i = blockIdx.x * blockDim.x + threadIdx.x;   // 0..65535
    const float4* row4 = (const float4*)row;
    // 32768 float4 per batch, 32 float4 per row
    out4[i] = row4[((i >> 15) << 5) | (i & 31)];
}

extern "C" void kernel_launch(void* const* d_in, const int* in_sizes, int n_in,
                              void* d_out, int out_size, void* d_ws, size_t ws_size,
                              hipStream_t stream) {
    const float* node   = (const float*)d_in[0];
    // d_in[1] prefer_emb, d_in[4..7] wq_p/wk_p: provably unused (attn == 1).
    const float* Wqkv_w = (const float*)d_in[2];
    const float* Wqkv_b = (const float*)d_in[3];
    const float* out_w  = (const float*)d_in[8];
    const float* out_b  = (const float*)d_in[9];

    float* ws     = (float*)d_ws;
    float* ne_sum = ws;          // 256 floats
    float* row    = ws + BB * DD; // 256 floats

    // ws is poisoned once and never re-poisoned; re-zero the atomic
    // accumulator every call so replays are deterministic.
    hipMemsetAsync(ne_sum, 0, BB * DD * sizeof(float), stream);

    k_colsum<<<dim3(64), dim3(128), 0, stream>>>(node, ne_sum);
    k_small<<<dim3(1), dim3(256), 0, stream>>>(ne_sum, Wqkv_w, Wqkv_b,
                                               out_w, out_b, row);
    k_bcast<<<dim3(256), dim3(256), 0, stream>>>(row, (float4*)d_out);
}

// Round 2
// 17.583 us; speedup vs baseline: 1.1291x; 1.1291x over previous
//
#include <hip/hip_runtime.h>

// Problem constants (B=2, M=10, N=1024, D=128, H=8, HD=16).
// Key identity: softmax over axis m followed by sum over the SAME axis m == 1
// everywhere, so attn is all-ones and the output is rank-1 per batch:
//   out[b, n, :] = ((sum_n node_emb[b,n,:]) @ Wv + N*bv) @ out_w + out_b
// where Wv = Wqkv_w[:, 2D:3D], bv = Wqkv_b[2D:3D].
// prefer_emb / wq_p / wk_p provably do not affect the output.
//
// 2 dispatches only:
//  k_colsum: partial column sums, disjoint writes (no atomics, no memset)
//  k_fused : every block redundantly finishes reduce+GEMV+GEMV (tiny),
//            then stores its slice of the broadcast output.

#define NN 1024
#define DD 128
#define TRIPLE (3 * DD)

// ---------------------------------------------------------------------------
// Kernel 1: partial[bk][d] = sum of 32 rows of flattened (2048 x 128) node_emb
// 64 blocks x 256 threads, float4 loads. Block bk covers rows [bk*32, bk*32+32).
// Rows 0..1023 = batch 0, 1024..2047 = batch 1 (so bk 0..31 -> b0, 32..63 -> b1).
// ---------------------------------------------------------------------------
__global__ void k_colsum(const float* __restrict__ node,
                         float* __restrict__ partial) {
    int bk = blockIdx.x;
    int t = threadIdx.x;
    int f4col = t & 31;          // which float4 of the 128-float row
    int rowsub = t >> 5;         // 0..7
    const float4* base = (const float4*)node;   // 32 float4 per row
    size_t row0 = (size_t)bk * 32 + rowsub;
    float4 acc = make_float4(0.f, 0.f, 0.f, 0.f);
#pragma unroll
    for (int it = 0; it < 4; ++it) {
        float4 v = base[(row0 + it * 8) * 32 + f4col];
        acc.x += v.x; acc.y += v.y; acc.z += v.z; acc.w += v.w;
    }
    __shared__ float4 s_red[256];
    s_red[t] = acc;
    __syncthreads();
    if (t < 32) {
        float4 a = s_red[t];
#pragma unroll
        for (int j = 1; j < 8; ++j) {
            float4 v = s_red[t + 32 * j];
            a.x += v.x; a.y += v.y; a.z += v.z; a.w += v.w;
        }
        ((float4*)partial)[bk * 32 + t] = a;   // partial[bk][4t..4t+3]
    }
}

// ---------------------------------------------------------------------------
// Kernel 2: 256 blocks x 256 threads. Each block redundantly computes:
//   ne_sum[b][d]  = sum_p partial[b*32+p][d]                (32 adds)
//   v_sum[b][d]   = ne_sum[b][:] @ Wv[:,d] + N*bv[d]        (128 FMA)
//   row[b][j]     = v_sum[b][:] @ out_w[:,j] + out_b[j]     (128 FMA)
// then writes its 1024-float slice of the broadcast output.
// Thread t -> (b = t>>7, d = t&127).
// ---------------------------------------------------------------------------
__global__ void k_fused(const float* __restrict__ partial,
                        const float* __restrict__ Wqkv_w,
                        const float* __restrict__ Wqkv_b,
                        const float* __restrict__ out_w,
                        const float* __restrict__ out_b,
                        float4* __restrict__ out4) {
    __shared__ float s_ne[256];
    __shared__ float s_vs[256];
    __shared__ float s_row[256];
    int t = threadIdx.x;
    int b = t >> 7;
    int d = t & (DD - 1);

    float ne = 0.f;
#pragma unroll 8
    for (int p = 0; p < 32; ++p)
        ne += partial[((b << 5) + p) * DD + d];
    s_ne[t] = ne;
    __syncthreads();

    float acc = Wqkv_b[2 * DD + d] * (float)NN;
#pragma unroll 8
    for (int c = 0; c < DD; ++c)
        acc += s_ne[(b << 7) + c] * Wqkv_w[c * TRIPLE + 2 * DD + d];
    s_vs[t] = acc;
    __syncthreads();

    float r = out_b[d];
#pragma unroll 8
    for (int c = 0; c < DD; ++c)
        r += s_vs[(b << 7) + c] * out_w[c * DD + d];
    s_row[t] = r;
    __syncthreads();

    // Broadcast: global float4 index gi covers 2*1024*32 = 65536 float4.
    // Batch = gi>>15, within-row float4 = gi&31.
    int gi = blockIdx.x * 256 + t;
    const float4* row4 = (const float4*)s_row;
    out4[gi] = row4[((gi >> 15) << 5) | (gi & 31)];
}

extern "C" void kernel_launch(void* const* d_in, const int* in_sizes, int n_in,
                              void* d_out, int out_size, void* d_ws, size_t ws_size,
                              hipStream_t stream) {
    const float* node   = (const float*)d_in[0];
    // d_in[1] prefer_emb, d_in[4..7] wq_p/wk_p: unused (attn == all-ones).
    const float* Wqkv_w = (const float*)d_in[2];
    const float* Wqkv_b = (const float*)d_in[3];
    const float* out_w  = (const float*)d_in[8];
    const float* out_b  = (const float*)d_in[9];

    float* partial = (float*)d_ws;   // 64*128 floats, fully overwritten each call

    k_colsum<<<dim3(64), dim3(256), 0, stream>>>(node, partial);
    k_fused<<<dim3(256), dim3(256), 0, stream>>>(partial, Wqkv_w, Wqkv_b,
                                                 out_w, out_b, (float4*)d_out);
}